// Round 18
// baseline (137.371 us; speedup 1.0000x reference)
//
#include <hip/hip_runtime.h>
#include <hip/hip_bf16.h>

#define DEV static __device__ __forceinline__

typedef __attribute__((ext_vector_type(4))) float f32x4;
typedef __attribute__((ext_vector_type(8))) short bf16x8;

DEV unsigned short f2bf(float f) {
  __hip_bfloat16 h = __float2bfloat16(f);  // native RNE cvt
  union { __hip_bfloat16 h; unsigned short u; } v; v.h = h;
  return v.u;
}
DEV float bf2f(unsigned short u) {
  union { unsigned u; float f; } v; v.u = ((unsigned)u) << 16;
  return v.f;
}
DEV void gl_lds16(const unsigned short* g, unsigned short* l) {
  __builtin_amdgcn_global_load_lds(
      (const __attribute__((address_space(1))) void*)g,
      (__attribute__((address_space(3))) void*)l, 16, 0, 0);
}

// ---------------- merged prepass: casts + 6-slice weight transpose ---------
struct T6 {
  const float* src[6];
  unsigned short* dst[6];
  int ldd[6];
};
__global__ void k_prep(const float* __restrict__ q, unsigned short* __restrict__ concat,
                       const float* __restrict__ mem, unsigned short* __restrict__ mem_bf,
                       T6 d) {
  __shared__ float tile[32][33];
  const int bid = blockIdx.x;
  if (bid < 7680) {
    const int i = bid * 256 + threadIdx.x;
    union { unsigned short u[4]; uint2 p; } o;
    if (i < 6144 * 256) {         // query: 8192x768 into [8192][1536] left half
      const int idx = i * 4;
      const int r = idx / 768, c = idx - r * 768;
      const float4 v = *(const float4*)(q + idx);
      o.u[0] = f2bf(v.x); o.u[1] = f2bf(v.y); o.u[2] = f2bf(v.z); o.u[3] = f2bf(v.w);
      *(uint2*)(concat + (size_t)r * 1536 + c) = o.p;
    } else {                      // memory: 2048x768 dense
      const int idx = (i - 6144 * 256) * 4;
      const float4 v = *(const float4*)(mem + idx);
      o.u[0] = f2bf(v.x); o.u[1] = f2bf(v.y); o.u[2] = f2bf(v.z); o.u[3] = f2bf(v.w);
      *(uint2*)(mem_bf + idx) = o.p;
    }
    return;
  }
  const int tb = bid - 7680;          // 6 slices x 576 tiles (24x24)
  const int z = tb / 576, rem = tb - z * 576;
  const float* src = d.src[z];
  unsigned short* dst = d.dst[z];
  const int ldd = d.ldd[z];
  const int n0 = (rem % 24) * 32, k0 = (rem / 24) * 32;
  const int tx = threadIdx.x & 31, ty = threadIdx.x >> 5;
#pragma unroll
  for (int i = 0; i < 4; i++)
    tile[ty + i * 8][tx] = src[(size_t)(k0 + ty + i * 8) * 768 + n0 + tx];
  __syncthreads();
#pragma unroll
  for (int i = 0; i < 4; i++)
    dst[(size_t)(n0 + ty + i * 8) * ldd + k0 + tx] = f2bf(tile[tx][ty + i * 8]);
}

// ---------------- GEMM core macros (256x64 tile, BK=64, 8 waves 4x2) -------
// Same proven 2-phase skeleton as the 127.8us champion (sync per K-tile,
// prefetch in flight across compute, both-sides XOR swizzle, XCD swizzle),
// but 256-row tiles raise flop per staged byte 43.7 -> 52.4 and halve B-panel
// re-reads (staging-traffic-bound theory). 512 threads; LDS 80 KB -> 2
// blocks x 8 waves = 16 waves/CU.
#define GEMM_STAGE(Aptr, lda, Bptr, ldb, buf, k0)                            \
  {                                                                          \
    _Pragma("unroll") for (int p = 0; p < 4; p++) {                          \
      const int ch = p * 512 + t;                                            \
      const int row = ch >> 3, s = ch & 7;                                   \
      gl_lds16(Aptr + (size_t)(r0 + row) * lda + (k0) + ((s ^ (row & 7)) * 8), \
               &Al[buf][ch * 8]);                                            \
    }                                                                        \
    {                                                                        \
      const int ch = t;                                                      \
      const int row = ch >> 3, s = ch & 7;                                   \
      gl_lds16(Bptr + (size_t)(c0 + row) * ldb + (k0) + ((s ^ (row & 7)) * 8), \
               &Bl[buf][ch * 8]);                                            \
    }                                                                        \
  }

#define GEMM_COMPUTE(cur)                                                    \
  _Pragma("unroll") for (int kb = 0; kb < 2; kb++) {                         \
    bf16x8 af[4], bfr[2];                                                    \
    _Pragma("unroll") for (int mi = 0; mi < 4; mi++) {                       \
      const int r = wr * 64 + mi * 16 + l15;                                 \
      const int s = (kb * 4 + l4) ^ (r & 7);                                 \
      af[mi] = *(const bf16x8*)&Al[cur][r * 64 + s * 8];                     \
    }                                                                        \
    _Pragma("unroll") for (int ni = 0; ni < 2; ni++) {                       \
      const int r = wc * 32 + ni * 16 + l15;                                 \
      const int s = (kb * 4 + l4) ^ (r & 7);                                 \
      bfr[ni] = *(const bf16x8*)&Bl[cur][r * 64 + s * 8];                    \
    }                                                                        \
    _Pragma("unroll") for (int mi = 0; mi < 4; mi++)                         \
      _Pragma("unroll") for (int ni = 0; ni < 2; ni++)                       \
        acc[mi][ni] = __builtin_amdgcn_mfma_f32_16x16x32_bf16(               \
            af[mi], bfr[ni], acc[mi][ni], 0, 0, 0);                          \
  }

#define GEMM_LOOP(Aptr, lda, Bptr, ldb, K)                                   \
  {                                                                          \
    const int nt = (K) >> 6;                                                 \
    GEMM_STAGE(Aptr, lda, Bptr, ldb, 0, 0);                                  \
    for (int tk = 0; tk < nt; ++tk) {                                        \
      const int cur = tk & 1;                                                \
      __syncthreads();                                                       \
      if (tk + 1 < nt) GEMM_STAGE(Aptr, lda, Bptr, ldb, cur ^ 1, (tk + 1) * 64); \
      GEMM_COMPUTE(cur);                                                     \
    }                                                                        \
  }

// ---------------- merged q-proj + kv-proj (one launch, runtime role) -------
// role 0 (swz < 384):  q_bf[8192,768] = concat[:, :768] @ Wqt^T, scale log2e/8
// role 1 (swz >= 384): [k|v] = mem_bf @ Wkvt^T; k -> k_bf, v -> vT scatter
__global__ __launch_bounds__(512) void k_gemm_qkv(
    const unsigned short* __restrict__ concat,
    const unsigned short* __restrict__ mem_bf,
    const unsigned short* __restrict__ Wqt,
    const unsigned short* __restrict__ Wkvt,
    const float* __restrict__ bq, const float* __restrict__ bk,
    const float* __restrict__ bv,
    unsigned short* __restrict__ q_bf, unsigned short* __restrict__ k_bf,
    unsigned short* __restrict__ vT) {
  __shared__ alignas(16) unsigned short Al[2][256 * 64];  // 64 KB
  __shared__ alignas(16) unsigned short Bl[2][64 * 64];   // 16 KB
  const int t = threadIdx.x;
  const int cpx = gridDim.x >> 3;                       // 576/8 = 72
  const int swz = (blockIdx.x & 7) * cpx + (blockIdx.x >> 3);
  const int role = swz < 384 ? 0 : 1;
  const int sub = role == 0 ? swz : swz - 384;
  const int gx = role == 0 ? 12 : 24;
  const int r0 = (sub / gx) * 256, c0 = (sub % gx) * 64;
  const unsigned short* A = role == 0 ? concat : mem_bf;
  const unsigned short* Bt = role == 0 ? Wqt : Wkvt;
  const int lda = role == 0 ? 1536 : 768;
  const int ldb = 768;
  const float scale = role == 0 ? 0.125f * 1.4426950408889634f : 1.f;
  const int lane = t & 63, l15 = lane & 15, l4 = lane >> 4;
  const int wid = t >> 6, wr = wid >> 1, wc = wid & 1;

  f32x4 acc[4][2];
#pragma unroll
  for (int mi = 0; mi < 4; mi++)
#pragma unroll
    for (int ni = 0; ni < 2; ni++) acc[mi][ni] = (f32x4){0.f, 0.f, 0.f, 0.f};

  GEMM_LOOP(A, lda, Bt, ldb, 768);

#pragma unroll
  for (int ni = 0; ni < 2; ni++) {
    const int c = c0 + wc * 32 + ni * 16 + l15;
    const float bvv = role == 0 ? bq[c] : (c < 768 ? bk[c] : bv[c - 768]);
#pragma unroll
    for (int mi = 0; mi < 4; mi++) {
      const int rbase = r0 + wr * 64 + mi * 16 + l4 * 4;
#pragma unroll
      for (int i = 0; i < 4; i++) {
        const int r = rbase + i;
        const float val = (acc[mi][ni][i] + bvv) * scale;
        if (role == 0) {
          q_bf[(size_t)r * 768 + c] = f2bf(val);
        } else if (c < 768) {
          k_bf[(size_t)r * 768 + c] = f2bf(val);
        } else {
          const int cc = c - 768;
          const int b = r >> 9, m = r & 511;
          const int h = cc >> 6, dd = cc & 63;
          vT[(((size_t)(b * 12 + h)) * 64 + dd) * 512 + m] = f2bf(val);
        }
      }
    }
  }
}

// ---------------- generic GEMM (out-proj EPI2, gate EPI3) ------------------
template <int EPI>
__global__ __launch_bounds__(512) void k_gemm(
    const unsigned short* __restrict__ A, int lda,
    const unsigned short* __restrict__ Bt, int ldb,
    const float* __restrict__ bias, int K, float scale,
    unsigned short* __restrict__ out0,
    const unsigned short* __restrict__ concat_in,
    const float* __restrict__ qy, float* __restrict__ dout, int gx) {
  __shared__ alignas(16) unsigned short Al[2][256 * 64];
  __shared__ alignas(16) unsigned short Bl[2][64 * 64];
  const int t = threadIdx.x;
  const int cpx = gridDim.x >> 3;
  const int swz = (blockIdx.x & 7) * cpx + (blockIdx.x >> 3);
  const int r0 = (swz / gx) * 256, c0 = (swz % gx) * 64;
  const int lane = t & 63, l15 = lane & 15, l4 = lane >> 4;
  const int wid = t >> 6, wr = wid >> 1, wc = wid & 1;

  f32x4 acc[4][2];
#pragma unroll
  for (int mi = 0; mi < 4; mi++)
#pragma unroll
    for (int ni = 0; ni < 2; ni++) acc[mi][ni] = (f32x4){0.f, 0.f, 0.f, 0.f};

  GEMM_LOOP(A, lda, Bt, ldb, K);

#pragma unroll
  for (int ni = 0; ni < 2; ni++) {
    const int c = c0 + wc * 32 + ni * 16 + l15;
    const float bvv = bias[c];
#pragma unroll
    for (int mi = 0; mi < 4; mi++) {
      const int rbase = r0 + wr * 64 + mi * 16 + l4 * 4;
#pragma unroll
      for (int i = 0; i < 4; i++) {
        const int r = rbase + i;
        const float val = acc[mi][ni][i] + bvv;
        if (EPI == 2) {
          out0[(size_t)r * 1536 + 768 + c] = f2bf(val);
        } else {
          const float g = 1.f / (1.f + __expf(-val));
          const float o = bf2f(concat_in[(size_t)r * 1536 + 768 + c]);
          const float q = qy[(size_t)r * 768 + c];
          dout[(size_t)r * 768 + c] = g * o + (1.f - g) * q;
        }
      }
    }
  }
}

// ---------------- fused attention (flash over M, no-max shifted softmax) ----
// CHUNK=64, double-buffered K/V staging, base-2 softmax (q pre-scaled log2e/8,
// bias pre-scaled log2e, shift -10). Champion form, unchanged.
__global__ __launch_bounds__(256, 3) void k_attn(
    const unsigned short* __restrict__ qbf,   // [B*S,768], pre-scaled log2e/8
    const unsigned short* __restrict__ kbf,   // [B*M,768]
    const unsigned short* __restrict__ vT,    // [B,H,64,512]
    const float* __restrict__ mscore,         // [B,512]
    unsigned short* __restrict__ aout) {      // [B*S,768]
  const int st = blockIdx.x, h = blockIdx.y, b = blockIdx.z;
  __shared__ float bias_s[512];
  __shared__ alignas(16) unsigned short Kl[2][64 * 64];  // 2 x 8 KB
  __shared__ alignas(16) unsigned short Vl[2][64 * 64];  // 2 x 8 KB
  __shared__ alignas(16) unsigned short P[4][16][72];    // 9.2 KB
  const int t = threadIdx.x;
  const int wid = t >> 6, lane = t & 63, l15 = lane & 15, l4 = lane >> 4;
  for (int i = t; i < 512; i += 256)
    bias_s[i] = (mscore[b * 512 + i] - 10.0f) * 1.4426950408889634f;

  const int srow = st * 64 + wid * 16;
  const unsigned short* qrow = qbf + ((size_t)(b * 2048 + srow + l15)) * 768 + h * 64;
  bf16x8 qa[2];
  qa[0] = *(const bf16x8*)(qrow + l4 * 8);
  qa[1] = *(const bf16x8*)(qrow + 32 + l4 * 8);

  const unsigned short* kbase = kbf + (size_t)(b * 512) * 768 + h * 64;
  const unsigned short* vbase = vT + ((size_t)(b * 12 + h)) * 64 * 512;

#define STAGE_A(buf, m0_)                                                     \
  {                                                                           \
    _Pragma("unroll") for (int p = 0; p < 2; p++) {                           \
      const int chk = p * 256 + t;                                            \
      const int row = chk >> 3, s = chk & 7;                                  \
      gl_lds16(kbase + (size_t)((m0_) + row) * 768 + ((s ^ (row & 7)) * 8),   \
               &Kl[buf][chk * 8]);                                            \
    }                                                                         \
    _Pragma("unroll") for (int p = 0; p < 2; p++) {                           \
      const int chk = p * 256 + t;                                            \
      const int row = chk >> 3, s = chk & 7;                                  \
      gl_lds16(vbase + (size_t)row * 512 + (m0_) + ((s ^ (row & 7)) * 8),     \
               &Vl[buf][chk * 8]);                                            \
    }                                                                         \
  }

  f32x4 O[4];
#pragma unroll
  for (int dt = 0; dt < 4; dt++) O[dt] = (f32x4){0.f, 0.f, 0.f, 0.f};
  float rs[4] = {0.f, 0.f, 0.f, 0.f};

  STAGE_A(0, 0);
  for (int ch = 0; ch < 8; ++ch) {
    const int cur = ch & 1;
    __syncthreads();  // drains staging (and bias_s on ch=0); prev buf consumed
    if (ch + 1 < 8) STAGE_A(cur ^ 1, (ch + 1) * 64);  // in flight across compute

    // ---- QK^T: scores [16 s x 64 m]; C-init = shifted scaled bias
    f32x4 s4[4];
#pragma unroll
    for (int tt = 0; tt < 4; tt++) {
      const float bs = bias_s[ch * 64 + tt * 16 + l15];
      s4[tt] = (f32x4){bs, bs, bs, bs};
    }
#pragma unroll
    for (int kb = 0; kb < 2; kb++)
#pragma unroll
      for (int tt = 0; tt < 4; tt++) {
        const int r = tt * 16 + l15;
        const bf16x8 bb = *(const bf16x8*)&Kl[cur][r * 64 + (((kb * 4 + l4) ^ (r & 7)) * 8)];
        s4[tt] = __builtin_amdgcn_mfma_f32_16x16x32_bf16(qa[kb], bb, s4[tt], 0, 0, 0);
      }

    // ---- p = exp2(s); accumulate row-sum; store P (bf16) for PV
#pragma unroll
    for (int tt = 0; tt < 4; tt++)
#pragma unroll
      for (int i = 0; i < 4; i++) {
        const float p = exp2f(s4[tt][i]);
        rs[i] += p;
        P[wid][l4 * 4 + i][tt * 16 + l15] = f2bf(p);
      }

    // ---- PV accumulate: O[16 x 64] += P[16 x 64] @ V[64 x 64]
#pragma unroll
    for (int mk = 0; mk < 2; mk++) {
      const bf16x8 pa = *(const bf16x8*)&P[wid][l15][mk * 32 + l4 * 8];
#pragma unroll
      for (int dt = 0; dt < 4; dt++) {
        const int r = dt * 16 + l15;
        const bf16x8 vb = *(const bf16x8*)&Vl[cur][r * 64 + (((mk * 4 + l4) ^ (r & 7)) * 8)];
        O[dt] = __builtin_amdgcn_mfma_f32_16x16x32_bf16(pa, vb, O[dt], 0, 0, 0);
      }
    }
  }
#undef STAGE_A

  // final row-sum reduction (once) + normalize + store
#pragma unroll
  for (int d = 1; d < 16; d <<= 1)
#pragma unroll
    for (int i = 0; i < 4; i++) rs[i] += __shfl_xor(rs[i], d);
  float rinv[4];
#pragma unroll
  for (int i = 0; i < 4; i++) rinv[i] = 1.f / rs[i];
  const size_t rbase = (size_t)(b * 2048 + srow + l4 * 4);
#pragma unroll
  for (int dt = 0; dt < 4; dt++)
#pragma unroll
    for (int i = 0; i < 4; i++)
      aout[(rbase + i) * 768 + h * 64 + dt * 16 + l15] = f2bf(O[dt][i] * rinv[i]);
}

extern "C" void kernel_launch(void* const* d_in, const int* in_sizes, int n_in,
                              void* d_out, int out_size, void* d_ws, size_t ws_size,
                              hipStream_t stream) {
  const float* query  = (const float*)d_in[0];
  const float* memory = (const float*)d_in[1];
  const float* mscore = (const float*)d_in[2];
  const float* Wq = (const float*)d_in[3];
  const float* bq = (const float*)d_in[4];
  const float* Wk = (const float*)d_in[5];
  const float* bk = (const float*)d_in[6];
  const float* Wv = (const float*)d_in[7];
  const float* bv = (const float*)d_in[8];
  const float* Wo = (const float*)d_in[9];
  const float* bo = (const float*)d_in[10];
  const float* Wg = (const float*)d_in[11];
  const float* bg = (const float*)d_in[12];
  float* dout = (float*)d_out;

  char* ws = (char*)d_ws;
  unsigned short* concat = (unsigned short*)ws; ws += (size_t)8192 * 1536 * 2;
  unsigned short* mem_bf = (unsigned short*)ws; ws += (size_t)2048 * 768 * 2;
  unsigned short* Wqt = (unsigned short*)ws;    ws += (size_t)768 * 768 * 2;
  unsigned short* Wkvt = (unsigned short*)ws;   ws += (size_t)1536 * 768 * 2;  // [Wk;Wv]^T
  unsigned short* Wot = (unsigned short*)ws;    ws += (size_t)768 * 768 * 2;
  unsigned short* Wgt = (unsigned short*)ws;    ws += (size_t)768 * 1536 * 2;
  unsigned short* q_bf = (unsigned short*)ws;   ws += (size_t)8192 * 768 * 2;
  unsigned short* k_bf = (unsigned short*)ws;   ws += (size_t)2048 * 768 * 2;
  unsigned short* vT = (unsigned short*)ws;     ws += (size_t)4 * 12 * 64 * 512 * 2;
  unsigned short* attn_bf = (unsigned short*)ws;

  // merged prepass: casts + 6 weight transposes (one launch)
  T6 td;
  td.src[0] = Wq;  td.dst[0] = Wqt;              td.ldd[0] = 768;
  td.src[1] = Wk;  td.dst[1] = Wkvt;             td.ldd[1] = 768;
  td.src[2] = Wv;  td.dst[2] = Wkvt + 768 * 768; td.ldd[2] = 768;
  td.src[3] = Wo;  td.dst[3] = Wot;              td.ldd[3] = 768;
  td.src[4] = Wg;  td.dst[4] = Wgt;              td.ldd[4] = 1536;
  td.src[5] = Wg + 768 * 768; td.dst[5] = Wgt + 768; td.ldd[5] = 1536;
  k_prep<<<7680 + 3456, 256, 0, stream>>>(query, concat, memory, mem_bf, td);

  // merged q-proj + kv-proj (one launch; 384 q-blocks + 192 kv-blocks, 256-row tiles)
  k_gemm_qkv<<<576, 512, 0, stream>>>(concat, mem_bf, Wqt, Wkvt,
                                      bq, bk, bv, q_bf, k_bf, vT);
  // attention
  k_attn<<<dim3(32, 12, 4), 256, 0, stream>>>(q_bf, k_bf, vT, mscore, attn_bf);
  // out projection -> concat right half (bf16)
  k_gemm<2><<<384, 512, 0, stream>>>(attn_bf, 768, Wot, 768, bo, 768, 1.f,
                                     concat, nullptr, nullptr, nullptr, 12);
  // gate GEMM + fused sigmoid mix -> d_out
  k_gemm<3><<<384, 512, 0, stream>>>(concat, 1536, Wgt, 1536, bg, 1536, 1.f,
                                     nullptr, concat, query, dout, 12);
}

// Round 19
// 130.701 us; speedup vs baseline: 1.0510x; 1.0510x over previous
//
#include <hip/hip_runtime.h>
#include <hip/hip_bf16.h>

#define DEV static __device__ __forceinline__

typedef __attribute__((ext_vector_type(4))) float f32x4;
typedef __attribute__((ext_vector_type(8))) short bf16x8;

DEV unsigned short f2bf(float f) {
  __hip_bfloat16 h = __float2bfloat16(f);  // native RNE cvt
  union { __hip_bfloat16 h; unsigned short u; } v; v.h = h;
  return v.u;
}
DEV float bf2f(unsigned short u) {
  union { unsigned u; float f; } v; v.u = ((unsigned)u) << 16;
  return v.f;
}
DEV void gl_lds16(const unsigned short* g, unsigned short* l) {
  __builtin_amdgcn_global_load_lds(
      (const __attribute__((address_space(1))) void*)g,
      (__attribute__((address_space(3))) void*)l, 16, 0, 0);
}

// ---------------- merged prepass: casts + 6-slice weight transpose ---------
struct T6 {
  const float* src[6];
  unsigned short* dst[6];
  int ldd[6];
};
__global__ void k_prep(const float* __restrict__ q, unsigned short* __restrict__ concat,
                       const float* __restrict__ mem, unsigned short* __restrict__ mem_bf,
                       T6 d) {
  __shared__ float tile[32][33];
  const int bid = blockIdx.x;
  if (bid < 7680) {
    const int i = bid * 256 + threadIdx.x;
    union { unsigned short u[4]; uint2 p; } o;
    if (i < 6144 * 256) {         // query: 8192x768 into [8192][1536] left half
      const int idx = i * 4;
      const int r = idx / 768, c = idx - r * 768;
      const float4 v = *(const float4*)(q + idx);
      o.u[0] = f2bf(v.x); o.u[1] = f2bf(v.y); o.u[2] = f2bf(v.z); o.u[3] = f2bf(v.w);
      *(uint2*)(concat + (size_t)r * 1536 + c) = o.p;
    } else {                      // memory: 2048x768 dense
      const int idx = (i - 6144 * 256) * 4;
      const float4 v = *(const float4*)(mem + idx);
      o.u[0] = f2bf(v.x); o.u[1] = f2bf(v.y); o.u[2] = f2bf(v.z); o.u[3] = f2bf(v.w);
      *(uint2*)(mem_bf + idx) = o.p;
    }
    return;
  }
  const int tb = bid - 7680;          // 6 slices x 576 tiles (24x24)
  const int z = tb / 576, rem = tb - z * 576;
  const float* src = d.src[z];
  unsigned short* dst = d.dst[z];
  const int ldd = d.ldd[z];
  const int n0 = (rem % 24) * 32, k0 = (rem / 24) * 32;
  const int tx = threadIdx.x & 31, ty = threadIdx.x >> 5;
#pragma unroll
  for (int i = 0; i < 4; i++)
    tile[ty + i * 8][tx] = src[(size_t)(k0 + ty + i * 8) * 768 + n0 + tx];
  __syncthreads();
#pragma unroll
  for (int i = 0; i < 4; i++)
    dst[(size_t)(n0 + ty + i * 8) * ldd + k0 + tx] = f2bf(tile[tx][ty + i * 8]);
}

// ---------------- GEMM core macros (128x64 tile, BK=64, 4 waves 2x2) -------
// Champion form (R13/R17, 127.8us): 2-phase __syncthreads loop, prefetch in
// flight across compute, both-sides XOR swizzle, XCD-chunked block swizzle.
#define GEMM_STAGE(Aptr, lda, Bptr, ldb, buf, k0)                            \
  {                                                                          \
    _Pragma("unroll") for (int p = 0; p < 4; p++) {                          \
      const int ch = p * 256 + t;                                            \
      const int row = ch >> 3, s = ch & 7;                                   \
      gl_lds16(Aptr + (size_t)(r0 + row) * lda + (k0) + ((s ^ (row & 7)) * 8), \
               &Al[buf][ch * 8]);                                            \
    }                                                                        \
    _Pragma("unroll") for (int p = 0; p < 2; p++) {                          \
      const int ch = p * 256 + t;                                            \
      const int row = ch >> 3, s = ch & 7;                                   \
      gl_lds16(Bptr + (size_t)(c0 + row) * ldb + (k0) + ((s ^ (row & 7)) * 8), \
               &Bl[buf][ch * 8]);                                            \
    }                                                                        \
  }

#define GEMM_COMPUTE(cur)                                                    \
  _Pragma("unroll") for (int kb = 0; kb < 2; kb++) {                         \
    bf16x8 af[4], bfr[2];                                                    \
    _Pragma("unroll") for (int mi = 0; mi < 4; mi++) {                       \
      const int r = wr * 64 + mi * 16 + l15;                                 \
      const int s = (kb * 4 + l4) ^ (r & 7);                                 \
      af[mi] = *(const bf16x8*)&Al[cur][r * 64 + s * 8];                     \
    }                                                                        \
    _Pragma("unroll") for (int ni = 0; ni < 2; ni++) {                       \
      const int r = wc * 32 + ni * 16 + l15;                                 \
      const int s = (kb * 4 + l4) ^ (r & 7);                                 \
      bfr[ni] = *(const bf16x8*)&Bl[cur][r * 64 + s * 8];                    \
    }                                                                        \
    _Pragma("unroll") for (int mi = 0; mi < 4; mi++)                         \
      _Pragma("unroll") for (int ni = 0; ni < 2; ni++)                       \
        acc[mi][ni] = __builtin_amdgcn_mfma_f32_16x16x32_bf16(               \
            af[mi], bfr[ni], acc[mi][ni], 0, 0, 0);                          \
  }

#define GEMM_LOOP(Aptr, lda, Bptr, ldb, K)                                   \
  {                                                                          \
    const int nt = (K) >> 6;                                                 \
    GEMM_STAGE(Aptr, lda, Bptr, ldb, 0, 0);                                  \
    for (int tk = 0; tk < nt; ++tk) {                                        \
      const int cur = tk & 1;                                                \
      __syncthreads();                                                       \
      if (tk + 1 < nt) GEMM_STAGE(Aptr, lda, Bptr, ldb, cur ^ 1, (tk + 1) * 64); \
      GEMM_COMPUTE(cur);                                                     \
    }                                                                        \
  }

// ---------------- merged q-proj + kv-proj (one launch, runtime role) -------
__global__ __launch_bounds__(256) void k_gemm_qkv(
    const unsigned short* __restrict__ concat,
    const unsigned short* __restrict__ mem_bf,
    const unsigned short* __restrict__ Wqt,
    const unsigned short* __restrict__ Wkvt,
    const float* __restrict__ bq, const float* __restrict__ bk,
    const float* __restrict__ bv,
    unsigned short* __restrict__ q_bf, unsigned short* __restrict__ k_bf,
    unsigned short* __restrict__ vT) {
  __shared__ alignas(16) unsigned short Al[2][128 * 64];  // 32 KB
  __shared__ alignas(16) unsigned short Bl[2][64 * 64];   // 16 KB
  const int t = threadIdx.x;
  const int cpx = gridDim.x >> 3;                       // 1152/8 = 144
  const int swz = (blockIdx.x & 7) * cpx + (blockIdx.x >> 3);
  const int role = swz < 768 ? 0 : 1;
  const int sub = role == 0 ? swz : swz - 768;
  const int gx = role == 0 ? 12 : 24;
  const int r0 = (sub / gx) * 128, c0 = (sub % gx) * 64;
  const unsigned short* A = role == 0 ? concat : mem_bf;
  const unsigned short* Bt = role == 0 ? Wqt : Wkvt;
  const int lda = role == 0 ? 1536 : 768;
  const int ldb = 768;
  const float scale = role == 0 ? 0.125f * 1.4426950408889634f : 1.f;
  const int lane = t & 63, l15 = lane & 15, l4 = lane >> 4;
  const int wid = t >> 6, wr = wid >> 1, wc = wid & 1;

  f32x4 acc[4][2];
#pragma unroll
  for (int mi = 0; mi < 4; mi++)
#pragma unroll
    for (int ni = 0; ni < 2; ni++) acc[mi][ni] = (f32x4){0.f, 0.f, 0.f, 0.f};

  GEMM_LOOP(A, lda, Bt, ldb, 768);

#pragma unroll
  for (int ni = 0; ni < 2; ni++) {
    const int c = c0 + wc * 32 + ni * 16 + l15;
    const float bvv = role == 0 ? bq[c] : (c < 768 ? bk[c] : bv[c - 768]);
#pragma unroll
    for (int mi = 0; mi < 4; mi++) {
      const int rbase = r0 + wr * 64 + mi * 16 + l4 * 4;
#pragma unroll
      for (int i = 0; i < 4; i++) {
        const int r = rbase + i;
        const float val = (acc[mi][ni][i] + bvv) * scale;
        if (role == 0) {
          q_bf[(size_t)r * 768 + c] = f2bf(val);
        } else if (c < 768) {
          k_bf[(size_t)r * 768 + c] = f2bf(val);
        } else {
          const int cc = c - 768;
          const int b = r >> 9, m = r & 511;
          const int h = cc >> 6, dd = cc & 63;
          vT[(((size_t)(b * 12 + h)) * 64 + dd) * 512 + m] = f2bf(val);
        }
      }
    }
  }
}

// ---------------- generic GEMM (out-proj EPI2, gate EPI3) ------------------
template <int EPI>
__global__ __launch_bounds__(256) void k_gemm(
    const unsigned short* __restrict__ A, int lda,
    const unsigned short* __restrict__ Bt, int ldb,
    const float* __restrict__ bias, int K, float scale,
    unsigned short* __restrict__ out0,
    const unsigned short* __restrict__ concat_in,
    const float* __restrict__ qy, float* __restrict__ dout, int gx) {
  __shared__ alignas(16) unsigned short Al[2][128 * 64];
  __shared__ alignas(16) unsigned short Bl[2][64 * 64];
  const int t = threadIdx.x;
  const int cpx = gridDim.x >> 3;
  const int swz = (blockIdx.x & 7) * cpx + (blockIdx.x >> 3);
  const int r0 = (swz / gx) * 128, c0 = (swz % gx) * 64;
  const int lane = t & 63, l15 = lane & 15, l4 = lane >> 4;
  const int wid = t >> 6, wr = wid >> 1, wc = wid & 1;

  f32x4 acc[4][2];
#pragma unroll
  for (int mi = 0; mi < 4; mi++)
#pragma unroll
    for (int ni = 0; ni < 2; ni++) acc[mi][ni] = (f32x4){0.f, 0.f, 0.f, 0.f};

  GEMM_LOOP(A, lda, Bt, ldb, K);

#pragma unroll
  for (int ni = 0; ni < 2; ni++) {
    const int c = c0 + wc * 32 + ni * 16 + l15;
    const float bvv = bias[c];
#pragma unroll
    for (int mi = 0; mi < 4; mi++) {
      const int rbase = r0 + wr * 64 + mi * 16 + l4 * 4;
#pragma unroll
      for (int i = 0; i < 4; i++) {
        const int r = rbase + i;
        const float val = acc[mi][ni][i] + bvv;
        if (EPI == 2) {
          out0[(size_t)r * 1536 + 768 + c] = f2bf(val);
        } else {
          const float g = 1.f / (1.f + __expf(-val));
          const float o = bf2f(concat_in[(size_t)r * 1536 + 768 + c]);
          const float q = qy[(size_t)r * 768 + c];
          dout[(size_t)r * 768 + c] = g * o + (1.f - g) * q;
        }
      }
    }
  }
}

// ---------------- fused attention (flash over M, no-max shifted softmax) ----
// CHUNK=64, double-buffered K/V staging, base-2 softmax. NEW: each block
// processes TWO 64-row s-tiles (128 q-rows) per staged K/V chunk -- 32 MFMA
// per wave per 16 KB staged (2x the champion), halving K/V re-stage traffic.
// P buffer is per-wave-private and consumed within each sub-tile iteration,
// so no extra barriers. VGPR ~124 (under the 128 cliff); grid 768 = 3/CU.
__global__ __launch_bounds__(256, 3) void k_attn(
    const unsigned short* __restrict__ qbf,   // [B*S,768], pre-scaled log2e/8
    const unsigned short* __restrict__ kbf,   // [B*M,768]
    const unsigned short* __restrict__ vT,    // [B,H,64,512]
    const float* __restrict__ mscore,         // [B,512]
    unsigned short* __restrict__ aout) {      // [B*S,768]
  const int st = blockIdx.x, h = blockIdx.y, b = blockIdx.z;
  __shared__ float bias_s[512];
  __shared__ alignas(16) unsigned short Kl[2][64 * 64];  // 2 x 8 KB
  __shared__ alignas(16) unsigned short Vl[2][64 * 64];  // 2 x 8 KB
  __shared__ alignas(16) unsigned short P[4][16][72];    // 9.2 KB
  const int t = threadIdx.x;
  const int wid = t >> 6, lane = t & 63, l15 = lane & 15, l4 = lane >> 4;
  for (int i = t; i < 512; i += 256)
    bias_s[i] = (mscore[b * 512 + i] - 10.0f) * 1.4426950408889634f;

  // two s-tiles per block: rows st*128 + sub*64 + wid*16
  const size_t qr0 = ((size_t)(b * 2048 + st * 128 + wid * 16 + l15)) * 768 + h * 64;
  bf16x8 qa[2][2];
#pragma unroll
  for (int sub = 0; sub < 2; sub++) {
#pragma unroll
    for (int kb = 0; kb < 2; kb++)
      qa[sub][kb] = *(const bf16x8*)(qbf + qr0 + (size_t)sub * 64 * 768 + kb * 32 + l4 * 8);
  }

  const unsigned short* kbase = kbf + (size_t)(b * 512) * 768 + h * 64;
  const unsigned short* vbase = vT + ((size_t)(b * 12 + h)) * 64 * 512;

#define STAGE_A(buf, m0_)                                                     \
  {                                                                           \
    _Pragma("unroll") for (int p = 0; p < 2; p++) {                           \
      const int chk = p * 256 + t;                                            \
      const int row = chk >> 3, s = chk & 7;                                  \
      gl_lds16(kbase + (size_t)((m0_) + row) * 768 + ((s ^ (row & 7)) * 8),   \
               &Kl[buf][chk * 8]);                                            \
    }                                                                         \
    _Pragma("unroll") for (int p = 0; p < 2; p++) {                           \
      const int chk = p * 256 + t;                                            \
      const int row = chk >> 3, s = chk & 7;                                  \
      gl_lds16(vbase + (size_t)row * 512 + (m0_) + ((s ^ (row & 7)) * 8),     \
               &Vl[buf][chk * 8]);                                            \
    }                                                                         \
  }

  f32x4 O[2][4];
#pragma unroll
  for (int sub = 0; sub < 2; sub++)
#pragma unroll
    for (int dt = 0; dt < 4; dt++) O[sub][dt] = (f32x4){0.f, 0.f, 0.f, 0.f};
  float rs[2][4] = {{0.f, 0.f, 0.f, 0.f}, {0.f, 0.f, 0.f, 0.f}};

  STAGE_A(0, 0);
  for (int ch = 0; ch < 8; ++ch) {
    const int cur = ch & 1;
    __syncthreads();  // drains staging (and bias_s on ch=0); prev buf consumed
    if (ch + 1 < 8) STAGE_A(cur ^ 1, (ch + 1) * 64);  // in flight across compute

#pragma unroll
    for (int sub = 0; sub < 2; sub++) {
      // ---- QK^T: scores [16 s x 64 m]; C-init = shifted scaled bias
      f32x4 s4[4];
#pragma unroll
      for (int tt = 0; tt < 4; tt++) {
        const float bs = bias_s[ch * 64 + tt * 16 + l15];
        s4[tt] = (f32x4){bs, bs, bs, bs};
      }
#pragma unroll
      for (int kb = 0; kb < 2; kb++)
#pragma unroll
        for (int tt = 0; tt < 4; tt++) {
          const int r = tt * 16 + l15;
          const bf16x8 bb = *(const bf16x8*)&Kl[cur][r * 64 + (((kb * 4 + l4) ^ (r & 7)) * 8)];
          s4[tt] = __builtin_amdgcn_mfma_f32_16x16x32_bf16(qa[sub][kb], bb, s4[tt], 0, 0, 0);
        }

      // ---- p = exp2(s); accumulate row-sum; store P (bf16) for PV
#pragma unroll
      for (int tt = 0; tt < 4; tt++)
#pragma unroll
        for (int i = 0; i < 4; i++) {
          const float p = exp2f(s4[tt][i]);
          rs[sub][i] += p;
          P[wid][l4 * 4 + i][tt * 16 + l15] = f2bf(p);
        }

      // ---- PV accumulate: O[16 x 64] += P[16 x 64] @ V[64 x 64]
#pragma unroll
      for (int mk = 0; mk < 2; mk++) {
        const bf16x8 pa = *(const bf16x8*)&P[wid][l15][mk * 32 + l4 * 8];
#pragma unroll
        for (int dt = 0; dt < 4; dt++) {
          const int r = dt * 16 + l15;
          const bf16x8 vb = *(const bf16x8*)&Vl[cur][r * 64 + (((mk * 4 + l4) ^ (r & 7)) * 8)];
          O[sub][dt] = __builtin_amdgcn_mfma_f32_16x16x32_bf16(pa, vb, O[sub][dt], 0, 0, 0);
        }
      }
    }
  }
#undef STAGE_A

  // final row-sum reduction (once) + normalize + store (both sub-tiles)
#pragma unroll
  for (int sub = 0; sub < 2; sub++) {
#pragma unroll
    for (int d = 1; d < 16; d <<= 1)
#pragma unroll
      for (int i = 0; i < 4; i++) rs[sub][i] += __shfl_xor(rs[sub][i], d);
    float rinv[4];
#pragma unroll
    for (int i = 0; i < 4; i++) rinv[i] = 1.f / rs[sub][i];
    const size_t rbase = (size_t)(b * 2048 + st * 128 + sub * 64 + wid * 16 + l4 * 4);
#pragma unroll
    for (int dt = 0; dt < 4; dt++)
#pragma unroll
      for (int i = 0; i < 4; i++)
        aout[(rbase + i) * 768 + h * 64 + dt * 16 + l15] = f2bf(O[sub][dt][i] * rinv[i]);
  }
}

extern "C" void kernel_launch(void* const* d_in, const int* in_sizes, int n_in,
                              void* d_out, int out_size, void* d_ws, size_t ws_size,
                              hipStream_t stream) {
  const float* query  = (const float*)d_in[0];
  const float* memory = (const float*)d_in[1];
  const float* mscore = (const float*)d_in[2];
  const float* Wq = (const float*)d_in[3];
  const float* bq = (const float*)d_in[4];
  const float* Wk = (const float*)d_in[5];
  const float* bk = (const float*)d_in[6];
  const float* Wv = (const float*)d_in[7];
  const float* bv = (const float*)d_in[8];
  const float* Wo = (const float*)d_in[9];
  const float* bo = (const float*)d_in[10];
  const float* Wg = (const float*)d_in[11];
  const float* bg = (const float*)d_in[12];
  float* dout = (float*)d_out;

  char* ws = (char*)d_ws;
  unsigned short* concat = (unsigned short*)ws; ws += (size_t)8192 * 1536 * 2;
  unsigned short* mem_bf = (unsigned short*)ws; ws += (size_t)2048 * 768 * 2;
  unsigned short* Wqt = (unsigned short*)ws;    ws += (size_t)768 * 768 * 2;
  unsigned short* Wkvt = (unsigned short*)ws;   ws += (size_t)1536 * 768 * 2;  // [Wk;Wv]^T
  unsigned short* Wot = (unsigned short*)ws;    ws += (size_t)768 * 768 * 2;
  unsigned short* Wgt = (unsigned short*)ws;    ws += (size_t)768 * 1536 * 2;
  unsigned short* q_bf = (unsigned short*)ws;   ws += (size_t)8192 * 768 * 2;
  unsigned short* k_bf = (unsigned short*)ws;   ws += (size_t)2048 * 768 * 2;
  unsigned short* vT = (unsigned short*)ws;     ws += (size_t)4 * 12 * 64 * 512 * 2;
  unsigned short* attn_bf = (unsigned short*)ws;

  // merged prepass: casts + 6 weight transposes (one launch)
  T6 td;
  td.src[0] = Wq;  td.dst[0] = Wqt;              td.ldd[0] = 768;
  td.src[1] = Wk;  td.dst[1] = Wkvt;             td.ldd[1] = 768;
  td.src[2] = Wv;  td.dst[2] = Wkvt + 768 * 768; td.ldd[2] = 768;
  td.src[3] = Wo;  td.dst[3] = Wot;              td.ldd[3] = 768;
  td.src[4] = Wg;  td.dst[4] = Wgt;              td.ldd[4] = 1536;
  td.src[5] = Wg + 768 * 768; td.dst[5] = Wgt + 768; td.ldd[5] = 1536;
  k_prep<<<7680 + 3456, 256, 0, stream>>>(query, concat, memory, mem_bf, td);

  // merged q-proj + kv-proj (one launch, 768 + 384 = 1152 blocks)
  k_gemm_qkv<<<1152, 256, 0, stream>>>(concat, mem_bf, Wqt, Wkvt,
                                       bq, bk, bv, q_bf, k_bf, vT);
  // attention (two 64-row s-tiles per block)
  k_attn<<<dim3(16, 12, 4), 256, 0, stream>>>(q_bf, k_bf, vT, mscore, attn_bf);
  // out projection -> concat right half (bf16)
  k_gemm<2><<<64 * 12, 256, 0, stream>>>(attn_bf, 768, Wot, 768, bo, 768, 1.f,
                                         concat, nullptr, nullptr, nullptr, 12);
  // gate GEMM + fused sigmoid mix -> d_out
  k_gemm<3><<<64 * 12, 256, 0, stream>>>(concat, 1536, Wgt, 1536, bg, 1536, 1.f,
                                         nullptr, concat, query, dout, 12);
}

// Round 20
// 127.329 us; speedup vs baseline: 1.0789x; 1.0265x over previous
//
#include <hip/hip_runtime.h>
#include <hip/hip_bf16.h>

#define DEV static __device__ __forceinline__

typedef __attribute__((ext_vector_type(4))) float f32x4;
typedef __attribute__((ext_vector_type(8))) short bf16x8;

DEV unsigned short f2bf(float f) {
  __hip_bfloat16 h = __float2bfloat16(f);  // native RNE cvt
  union { __hip_bfloat16 h; unsigned short u; } v; v.h = h;
  return v.u;
}
DEV float bf2f(unsigned short u) {
  union { unsigned u; float f; } v; v.u = ((unsigned)u) << 16;
  return v.f;
}
DEV void gl_lds16(const unsigned short* g, unsigned short* l) {
  __builtin_amdgcn_global_load_lds(
      (const __attribute__((address_space(1))) void*)g,
      (__attribute__((address_space(3))) void*)l, 16, 0, 0);
}

// ---------------- merged prepass: casts + 6-slice weight transpose ---------
struct T6 {
  const float* src[6];
  unsigned short* dst[6];
  int ldd[6];
};
__global__ void k_prep(const float* __restrict__ q, unsigned short* __restrict__ concat,
                       const float* __restrict__ mem, unsigned short* __restrict__ mem_bf,
                       T6 d) {
  __shared__ float tile[32][33];
  const int bid = blockIdx.x;
  if (bid < 7680) {
    const int i = bid * 256 + threadIdx.x;
    union { unsigned short u[4]; uint2 p; } o;
    if (i < 6144 * 256) {         // query: 8192x768 into [8192][1536] left half
      const int idx = i * 4;
      const int r = idx / 768, c = idx - r * 768;
      const float4 v = *(const float4*)(q + idx);
      o.u[0] = f2bf(v.x); o.u[1] = f2bf(v.y); o.u[2] = f2bf(v.z); o.u[3] = f2bf(v.w);
      *(uint2*)(concat + (size_t)r * 1536 + c) = o.p;
    } else {                      // memory: 2048x768 dense
      const int idx = (i - 6144 * 256) * 4;
      const float4 v = *(const float4*)(mem + idx);
      o.u[0] = f2bf(v.x); o.u[1] = f2bf(v.y); o.u[2] = f2bf(v.z); o.u[3] = f2bf(v.w);
      *(uint2*)(mem_bf + idx) = o.p;
    }
    return;
  }
  const int tb = bid - 7680;          // 6 slices x 576 tiles (24x24)
  const int z = tb / 576, rem = tb - z * 576;
  const float* src = d.src[z];
  unsigned short* dst = d.dst[z];
  const int ldd = d.ldd[z];
  const int n0 = (rem % 24) * 32, k0 = (rem / 24) * 32;
  const int tx = threadIdx.x & 31, ty = threadIdx.x >> 5;
#pragma unroll
  for (int i = 0; i < 4; i++)
    tile[ty + i * 8][tx] = src[(size_t)(k0 + ty + i * 8) * 768 + n0 + tx];
  __syncthreads();
#pragma unroll
  for (int i = 0; i < 4; i++)
    dst[(size_t)(n0 + ty + i * 8) * ldd + k0 + tx] = f2bf(tile[tx][ty + i * 8]);
}

// ---------------- GEMM core macros (128x64 tile, BK=64, 4 waves 2x2) -------
// Champion form (127.8us, reproduced): 2-phase __syncthreads loop, prefetch
// in flight across compute, both-sides XOR swizzle (slot^(row&7)) -> 0 bank
// conflicts, XCD-chunked block swizzle.
#define GEMM_STAGE(Aptr, lda, Bptr, ldb, buf, k0)                            \
  {                                                                          \
    _Pragma("unroll") for (int p = 0; p < 4; p++) {                          \
      const int ch = p * 256 + t;                                            \
      const int row = ch >> 3, s = ch & 7;                                   \
      gl_lds16(Aptr + (size_t)(r0 + row) * lda + (k0) + ((s ^ (row & 7)) * 8), \
               &Al[buf][ch * 8]);                                            \
    }                                                                        \
    _Pragma("unroll") for (int p = 0; p < 2; p++) {                          \
      const int ch = p * 256 + t;                                            \
      const int row = ch >> 3, s = ch & 7;                                   \
      gl_lds16(Bptr + (size_t)(c0 + row) * ldb + (k0) + ((s ^ (row & 7)) * 8), \
               &Bl[buf][ch * 8]);                                            \
    }                                                                        \
  }

#define GEMM_COMPUTE(cur)                                                    \
  _Pragma("unroll") for (int kb = 0; kb < 2; kb++) {                         \
    bf16x8 af[4], bfr[2];                                                    \
    _Pragma("unroll") for (int mi = 0; mi < 4; mi++) {                       \
      const int r = wr * 64 + mi * 16 + l15;                                 \
      const int s = (kb * 4 + l4) ^ (r & 7);                                 \
      af[mi] = *(const bf16x8*)&Al[cur][r * 64 + s * 8];                     \
    }                                                                        \
    _Pragma("unroll") for (int ni = 0; ni < 2; ni++) {                       \
      const int r = wc * 32 + ni * 16 + l15;                                 \
      const int s = (kb * 4 + l4) ^ (r & 7);                                 \
      bfr[ni] = *(const bf16x8*)&Bl[cur][r * 64 + s * 8];                    \
    }                                                                        \
    _Pragma("unroll") for (int mi = 0; mi < 4; mi++)                         \
      _Pragma("unroll") for (int ni = 0; ni < 2; ni++)                       \
        acc[mi][ni] = __builtin_amdgcn_mfma_f32_16x16x32_bf16(               \
            af[mi], bfr[ni], acc[mi][ni], 0, 0, 0);                          \
  }

#define GEMM_LOOP(Aptr, lda, Bptr, ldb, K)                                   \
  {                                                                          \
    const int nt = (K) >> 6;                                                 \
    GEMM_STAGE(Aptr, lda, Bptr, ldb, 0, 0);                                  \
    for (int tk = 0; tk < nt; ++tk) {                                        \
      const int cur = tk & 1;                                                \
      __syncthreads();                                                       \
      if (tk + 1 < nt) GEMM_STAGE(Aptr, lda, Bptr, ldb, cur ^ 1, (tk + 1) * 64); \
      GEMM_COMPUTE(cur);                                                     \
    }                                                                        \
  }

// ---------------- merged q-proj + kv-proj (one launch, runtime role) -------
__global__ __launch_bounds__(256) void k_gemm_qkv(
    const unsigned short* __restrict__ concat,
    const unsigned short* __restrict__ mem_bf,
    const unsigned short* __restrict__ Wqt,
    const unsigned short* __restrict__ Wkvt,
    const float* __restrict__ bq, const float* __restrict__ bk,
    const float* __restrict__ bv,
    unsigned short* __restrict__ q_bf, unsigned short* __restrict__ k_bf,
    unsigned short* __restrict__ vT) {
  __shared__ alignas(16) unsigned short Al[2][128 * 64];  // 32 KB
  __shared__ alignas(16) unsigned short Bl[2][64 * 64];   // 16 KB
  const int t = threadIdx.x;
  const int cpx = gridDim.x >> 3;                       // 1152/8 = 144
  const int swz = (blockIdx.x & 7) * cpx + (blockIdx.x >> 3);
  const int role = swz < 768 ? 0 : 1;
  const int sub = role == 0 ? swz : swz - 768;
  const int gx = role == 0 ? 12 : 24;
  const int r0 = (sub / gx) * 128, c0 = (sub % gx) * 64;
  const unsigned short* A = role == 0 ? concat : mem_bf;
  const unsigned short* Bt = role == 0 ? Wqt : Wkvt;
  const int lda = role == 0 ? 1536 : 768;
  const int ldb = 768;
  const float scale = role == 0 ? 0.125f * 1.4426950408889634f : 1.f;
  const int lane = t & 63, l15 = lane & 15, l4 = lane >> 4;
  const int wid = t >> 6, wr = wid >> 1, wc = wid & 1;

  f32x4 acc[4][2];
#pragma unroll
  for (int mi = 0; mi < 4; mi++)
#pragma unroll
    for (int ni = 0; ni < 2; ni++) acc[mi][ni] = (f32x4){0.f, 0.f, 0.f, 0.f};

  GEMM_LOOP(A, lda, Bt, ldb, 768);

#pragma unroll
  for (int ni = 0; ni < 2; ni++) {
    const int c = c0 + wc * 32 + ni * 16 + l15;
    const float bvv = role == 0 ? bq[c] : (c < 768 ? bk[c] : bv[c - 768]);
#pragma unroll
    for (int mi = 0; mi < 4; mi++) {
      const int rbase = r0 + wr * 64 + mi * 16 + l4 * 4;
#pragma unroll
      for (int i = 0; i < 4; i++) {
        const int r = rbase + i;
        const float val = (acc[mi][ni][i] + bvv) * scale;
        if (role == 0) {
          q_bf[(size_t)r * 768 + c] = f2bf(val);
        } else if (c < 768) {
          k_bf[(size_t)r * 768 + c] = f2bf(val);
        } else {
          const int cc = c - 768;
          const int b = r >> 9, m = r & 511;
          const int h = cc >> 6, dd = cc & 63;
          vT[(((size_t)(b * 12 + h)) * 64 + dd) * 512 + m] = f2bf(val);
        }
      }
    }
  }
}

// ---------------- generic GEMM (out-proj EPI2, gate EPI3) ------------------
template <int EPI>
__global__ __launch_bounds__(256) void k_gemm(
    const unsigned short* __restrict__ A, int lda,
    const unsigned short* __restrict__ Bt, int ldb,
    const float* __restrict__ bias, int K, float scale,
    unsigned short* __restrict__ out0,
    const unsigned short* __restrict__ concat_in,
    const float* __restrict__ qy, float* __restrict__ dout, int gx) {
  __shared__ alignas(16) unsigned short Al[2][128 * 64];
  __shared__ alignas(16) unsigned short Bl[2][64 * 64];
  const int t = threadIdx.x;
  const int cpx = gridDim.x >> 3;
  const int swz = (blockIdx.x & 7) * cpx + (blockIdx.x >> 3);
  const int r0 = (swz / gx) * 128, c0 = (swz % gx) * 64;
  const int lane = t & 63, l15 = lane & 15, l4 = lane >> 4;
  const int wid = t >> 6, wr = wid >> 1, wc = wid & 1;

  f32x4 acc[4][2];
#pragma unroll
  for (int mi = 0; mi < 4; mi++)
#pragma unroll
    for (int ni = 0; ni < 2; ni++) acc[mi][ni] = (f32x4){0.f, 0.f, 0.f, 0.f};

  GEMM_LOOP(A, lda, Bt, ldb, K);

#pragma unroll
  for (int ni = 0; ni < 2; ni++) {
    const int c = c0 + wc * 32 + ni * 16 + l15;
    const float bvv = bias[c];
#pragma unroll
    for (int mi = 0; mi < 4; mi++) {
      const int rbase = r0 + wr * 64 + mi * 16 + l4 * 4;
#pragma unroll
      for (int i = 0; i < 4; i++) {
        const int r = rbase + i;
        const float val = acc[mi][ni][i] + bvv;
        if (EPI == 2) {
          out0[(size_t)r * 1536 + 768 + c] = f2bf(val);
        } else {
          const float g = 1.f / (1.f + __expf(-val));
          const float o = bf2f(concat_in[(size_t)r * 1536 + 768 + c]);
          const float q = qy[(size_t)r * 768 + c];
          dout[(size_t)r * 768 + c] = g * o + (1.f - g) * q;
        }
      }
    }
  }
}

// ---------------- fused attention (flash over M, no-max shifted softmax) ----
// CHUNK=64, double-buffered K/V staging, base-2 softmax (q pre-scaled log2e/8,
// bias pre-scaled log2e, shift -10). Champion form.
__global__ __launch_bounds__(256, 3) void k_attn(
    const unsigned short* __restrict__ qbf,   // [B*S,768], pre-scaled log2e/8
    const unsigned short* __restrict__ kbf,   // [B*M,768]
    const unsigned short* __restrict__ vT,    // [B,H,64,512]
    const float* __restrict__ mscore,         // [B,512]
    unsigned short* __restrict__ aout) {      // [B*S,768]
  const int st = blockIdx.x, h = blockIdx.y, b = blockIdx.z;
  __shared__ float bias_s[512];
  __shared__ alignas(16) unsigned short Kl[2][64 * 64];  // 2 x 8 KB
  __shared__ alignas(16) unsigned short Vl[2][64 * 64];  // 2 x 8 KB
  __shared__ alignas(16) unsigned short P[4][16][72];    // 9.2 KB
  const int t = threadIdx.x;
  const int wid = t >> 6, lane = t & 63, l15 = lane & 15, l4 = lane >> 4;
  for (int i = t; i < 512; i += 256)
    bias_s[i] = (mscore[b * 512 + i] - 10.0f) * 1.4426950408889634f;

  const int srow = st * 64 + wid * 16;
  const unsigned short* qrow = qbf + ((size_t)(b * 2048 + srow + l15)) * 768 + h * 64;
  bf16x8 qa[2];
  qa[0] = *(const bf16x8*)(qrow + l4 * 8);
  qa[1] = *(const bf16x8*)(qrow + 32 + l4 * 8);

  const unsigned short* kbase = kbf + (size_t)(b * 512) * 768 + h * 64;
  const unsigned short* vbase = vT + ((size_t)(b * 12 + h)) * 64 * 512;

#define STAGE_A(buf, m0_)                                                     \
  {                                                                           \
    _Pragma("unroll") for (int p = 0; p < 2; p++) {                           \
      const int chk = p * 256 + t;                                            \
      const int row = chk >> 3, s = chk & 7;                                  \
      gl_lds16(kbase + (size_t)((m0_) + row) * 768 + ((s ^ (row & 7)) * 8),   \
               &Kl[buf][chk * 8]);                                            \
    }                                                                         \
    _Pragma("unroll") for (int p = 0; p < 2; p++) {                           \
      const int chk = p * 256 + t;                                            \
      const int row = chk >> 3, s = chk & 7;                                  \
      gl_lds16(vbase + (size_t)row * 512 + (m0_) + ((s ^ (row & 7)) * 8),     \
               &Vl[buf][chk * 8]);                                            \
    }                                                                         \
  }

  f32x4 O[4];
#pragma unroll
  for (int dt = 0; dt < 4; dt++) O[dt] = (f32x4){0.f, 0.f, 0.f, 0.f};
  float rs[4] = {0.f, 0.f, 0.f, 0.f};

  STAGE_A(0, 0);
  for (int ch = 0; ch < 8; ++ch) {
    const int cur = ch & 1;
    __syncthreads();  // drains staging (and bias_s on ch=0); prev buf consumed
    if (ch + 1 < 8) STAGE_A(cur ^ 1, (ch + 1) * 64);  // in flight across compute

    // ---- QK^T: scores [16 s x 64 m]; C-init = shifted scaled bias
    f32x4 s4[4];
#pragma unroll
    for (int tt = 0; tt < 4; tt++) {
      const float bs = bias_s[ch * 64 + tt * 16 + l15];
      s4[tt] = (f32x4){bs, bs, bs, bs};
    }
#pragma unroll
    for (int kb = 0; kb < 2; kb++)
#pragma unroll
      for (int tt = 0; tt < 4; tt++) {
        const int r = tt * 16 + l15;
        const bf16x8 bb = *(const bf16x8*)&Kl[cur][r * 64 + (((kb * 4 + l4) ^ (r & 7)) * 8)];
        s4[tt] = __builtin_amdgcn_mfma_f32_16x16x32_bf16(qa[kb], bb, s4[tt], 0, 0, 0);
      }

    // ---- p = exp2(s); accumulate row-sum; store P (bf16) for PV
#pragma unroll
    for (int tt = 0; tt < 4; tt++)
#pragma unroll
      for (int i = 0; i < 4; i++) {
        const float p = exp2f(s4[tt][i]);
        rs[i] += p;
        P[wid][l4 * 4 + i][tt * 16 + l15] = f2bf(p);
      }

    // ---- PV accumulate: O[16 x 64] += P[16 x 64] @ V[64 x 64]
#pragma unroll
    for (int mk = 0; mk < 2; mk++) {
      const bf16x8 pa = *(const bf16x8*)&P[wid][l15][mk * 32 + l4 * 8];
#pragma unroll
      for (int dt = 0; dt < 4; dt++) {
        const int r = dt * 16 + l15;
        const bf16x8 vb = *(const bf16x8*)&Vl[cur][r * 64 + (((mk * 4 + l4) ^ (r & 7)) * 8)];
        O[dt] = __builtin_amdgcn_mfma_f32_16x16x32_bf16(pa, vb, O[dt], 0, 0, 0);
      }
    }
  }
#undef STAGE_A

  // final row-sum reduction (once) + normalize + store
#pragma unroll
  for (int d = 1; d < 16; d <<= 1)
#pragma unroll
    for (int i = 0; i < 4; i++) rs[i] += __shfl_xor(rs[i], d);
  float rinv[4];
#pragma unroll
  for (int i = 0; i < 4; i++) rinv[i] = 1.f / rs[i];
  const size_t rbase = (size_t)(b * 2048 + srow + l4 * 4);
#pragma unroll
  for (int dt = 0; dt < 4; dt++)
#pragma unroll
    for (int i = 0; i < 4; i++)
      aout[(rbase + i) * 768 + h * 64 + dt * 16 + l15] = f2bf(O[dt][i] * rinv[i]);
}

extern "C" void kernel_launch(void* const* d_in, const int* in_sizes, int n_in,
                              void* d_out, int out_size, void* d_ws, size_t ws_size,
                              hipStream_t stream) {
  const float* query  = (const float*)d_in[0];
  const float* memory = (const float*)d_in[1];
  const float* mscore = (const float*)d_in[2];
  const float* Wq = (const float*)d_in[3];
  const float* bq = (const float*)d_in[4];
  const float* Wk = (const float*)d_in[5];
  const float* bk = (const float*)d_in[6];
  const float* Wv = (const float*)d_in[7];
  const float* bv = (const float*)d_in[8];
  const float* Wo = (const float*)d_in[9];
  const float* bo = (const float*)d_in[10];
  const float* Wg = (const float*)d_in[11];
  const float* bg = (const float*)d_in[12];
  float* dout = (float*)d_out;

  char* ws = (char*)d_ws;
  unsigned short* concat = (unsigned short*)ws; ws += (size_t)8192 * 1536 * 2;
  unsigned short* mem_bf = (unsigned short*)ws; ws += (size_t)2048 * 768 * 2;
  unsigned short* Wqt = (unsigned short*)ws;    ws += (size_t)768 * 768 * 2;
  unsigned short* Wkvt = (unsigned short*)ws;   ws += (size_t)1536 * 768 * 2;  // [Wk;Wv]^T
  unsigned short* Wot = (unsigned short*)ws;    ws += (size_t)768 * 768 * 2;
  unsigned short* Wgt = (unsigned short*)ws;    ws += (size_t)768 * 1536 * 2;
  unsigned short* q_bf = (unsigned short*)ws;   ws += (size_t)8192 * 768 * 2;
  unsigned short* k_bf = (unsigned short*)ws;   ws += (size_t)2048 * 768 * 2;
  unsigned short* vT = (unsigned short*)ws;     ws += (size_t)4 * 12 * 64 * 512 * 2;
  unsigned short* attn_bf = (unsigned short*)ws;

  // merged prepass: casts + 6 weight transposes (one launch)
  T6 td;
  td.src[0] = Wq;  td.dst[0] = Wqt;              td.ldd[0] = 768;
  td.src[1] = Wk;  td.dst[1] = Wkvt;             td.ldd[1] = 768;
  td.src[2] = Wv;  td.dst[2] = Wkvt + 768 * 768; td.ldd[2] = 768;
  td.src[3] = Wo;  td.dst[3] = Wot;              td.ldd[3] = 768;
  td.src[4] = Wg;  td.dst[4] = Wgt;              td.ldd[4] = 1536;
  td.src[5] = Wg + 768 * 768; td.dst[5] = Wgt + 768; td.ldd[5] = 1536;
  k_prep<<<7680 + 3456, 256, 0, stream>>>(query, concat, memory, mem_bf, td);

  // merged q-proj + kv-proj (one launch, 768 + 384 = 1152 blocks)
  k_gemm_qkv<<<1152, 256, 0, stream>>>(concat, mem_bf, Wqt, Wkvt,
                                       bq, bk, bv, q_bf, k_bf, vT);
  // attention
  k_attn<<<dim3(32, 12, 4), 256, 0, stream>>>(q_bf, k_bf, vT, mscore, attn_bf);
  // out projection -> concat right half (bf16)
  k_gemm<2><<<64 * 12, 256, 0, stream>>>(attn_bf, 768, Wot, 768, bo, 768, 1.f,
                                         concat, nullptr, nullptr, nullptr, 12);
  // gate GEMM + fused sigmoid mix -> d_out
  k_gemm<3><<<64 * 12, 256, 0, stream>>>(concat, 1536, Wgt, 1536, bg, 1536, 1.f,
                                         nullptr, concat, query, dout, 12);
}